// Round 1
// baseline (1204.022 us; speedup 1.0000x reference)
//
#include <hip/hip_runtime.h>
#include <hip/hip_bf16.h>

#define NROWS 2048
#define HID   256
#define OBSD  128

// ---------------- generic fp32 tiled GEMM: C = epilogue(A@W [+Cin] [+bias]) ----------------
// A: M x K (row-major, lda=K), W: K x 256 (row-major, ldw=256), C: M x 256.
// flags: 1=accumulate Cin, 2=add bias, 4=relu, 8=select (deg<=0 -> fallback row)
#define F_ACC 1
#define F_BIAS 2
#define F_RELU 4
#define F_SEL 8

__global__ __launch_bounds__(256) void gemm64(
    const float* __restrict__ A, const float* __restrict__ W,
    const float* __restrict__ bias, const float* __restrict__ Cin,
    float* __restrict__ C, int K, int flags,
    const float* __restrict__ deg, const float* __restrict__ fallback)
{
    __shared__ float As[16][68];
    __shared__ float Ws[16][68];
    const int bm = blockIdx.x, bn = blockIdx.y;
    const int tid = threadIdx.x;
    const int m_l = tid >> 2, k_l4 = (tid & 3) << 2;   // A-tile load coords
    const int k_w = tid >> 4, n_l4 = (tid & 15) << 2;  // W-tile load coords
    const int ty = tid >> 4, tx = tid & 15;            // compute coords

    float acc[4][4];
#pragma unroll
    for (int i = 0; i < 4; ++i)
#pragma unroll
        for (int j = 0; j < 4; ++j) acc[i][j] = 0.f;

    const float* Ab = A + (size_t)(bm * 64 + m_l) * K;
    const float* Wb = W + bn * 64;

    for (int k0 = 0; k0 < K; k0 += 16) {
        float4 av = *(const float4*)(Ab + k0 + k_l4);
        float4 wv = *(const float4*)(Wb + (size_t)(k0 + k_w) * HID + n_l4);
        __syncthreads();  // previous iter's reads done before overwrite
        As[k_l4 + 0][m_l] = av.x;
        As[k_l4 + 1][m_l] = av.y;
        As[k_l4 + 2][m_l] = av.z;
        As[k_l4 + 3][m_l] = av.w;
        *(float4*)&Ws[k_w][n_l4] = wv;
        __syncthreads();
#pragma unroll
        for (int kk = 0; kk < 16; ++kk) {
            float4 a = *(const float4*)&As[kk][ty << 2];
            float4 w = *(const float4*)&Ws[kk][tx << 2];
            acc[0][0] += a.x * w.x; acc[0][1] += a.x * w.y; acc[0][2] += a.x * w.z; acc[0][3] += a.x * w.w;
            acc[1][0] += a.y * w.x; acc[1][1] += a.y * w.y; acc[1][2] += a.y * w.z; acc[1][3] += a.y * w.w;
            acc[2][0] += a.z * w.x; acc[2][1] += a.z * w.y; acc[2][2] += a.z * w.z; acc[2][3] += a.z * w.w;
            acc[3][0] += a.w * w.x; acc[3][1] += a.w * w.y; acc[3][2] += a.w * w.z; acc[3][3] += a.w * w.w;
        }
    }

    const int col4 = bn * 64 + (tx << 2);
    float4 bv = make_float4(0.f, 0.f, 0.f, 0.f);
    if (flags & F_BIAS) bv = *(const float4*)(bias + col4);
#pragma unroll
    for (int mi = 0; mi < 4; ++mi) {
        const int row = bm * 64 + (ty << 2) + mi;
        float4 r = make_float4(acc[mi][0], acc[mi][1], acc[mi][2], acc[mi][3]);
        if (flags & F_ACC) {
            float4 p = *(const float4*)(Cin + (size_t)row * HID + col4);
            r.x += p.x; r.y += p.y; r.z += p.z; r.w += p.w;
        }
        r.x += bv.x; r.y += bv.y; r.z += bv.z; r.w += bv.w;
        if (flags & F_RELU) {
            r.x = fmaxf(r.x, 0.f); r.y = fmaxf(r.y, 0.f);
            r.z = fmaxf(r.z, 0.f); r.w = fmaxf(r.w, 0.f);
        }
        if (flags & F_SEL) {
            if (deg[row] <= 0.f)
                r = *(const float4*)(fallback + (size_t)row * HID + col4);
        }
        *(float4*)(C + (size_t)row * HID + col4) = r;
    }
}

// ---------------- masked neighbor mean + degree ----------------
// neigh[i][h] = sum_{j: adj[i][j]>0, j!=i} indiv[j][h] / max(deg,1); deg[i] = count
__global__ __launch_bounds__(256) void neigh_k(
    const int* __restrict__ adj, const float* __restrict__ indiv,
    float* __restrict__ neigh, float* __restrict__ deg)
{
    const int i0 = blockIdx.x * 4;
    const int t = threadIdx.x;
    float a0 = 0.f, a1 = 0.f, a2 = 0.f, a3 = 0.f;
    int c0 = 0, c1 = 0, c2 = 0, c3 = 0;
    const int* r0 = adj + (size_t)(i0 + 0) * NROWS;
    const int* r1 = adj + (size_t)(i0 + 1) * NROWS;
    const int* r2 = adj + (size_t)(i0 + 2) * NROWS;
    const int* r3 = adj + (size_t)(i0 + 3) * NROWS;
#pragma unroll 4
    for (int j = 0; j < NROWS; ++j) {
        float v = indiv[(size_t)j * HID + t];
        int m0 = (r0[j] > 0) & (j != i0 + 0);
        int m1 = (r1[j] > 0) & (j != i0 + 1);
        int m2 = (r2[j] > 0) & (j != i0 + 2);
        int m3 = (r3[j] > 0) & (j != i0 + 3);
        if (m0) { a0 += v; } c0 += m0;
        if (m1) { a1 += v; } c1 += m1;
        if (m2) { a2 += v; } c2 += m2;
        if (m3) { a3 += v; } c3 += m3;
    }
    neigh[(size_t)(i0 + 0) * HID + t] = a0 / fmaxf((float)c0, 1.f);
    neigh[(size_t)(i0 + 1) * HID + t] = a1 / fmaxf((float)c1, 1.f);
    neigh[(size_t)(i0 + 2) * HID + t] = a2 / fmaxf((float)c2, 1.f);
    neigh[(size_t)(i0 + 3) * HID + t] = a3 / fmaxf((float)c3, 1.f);
    if (t == 0) {
        deg[i0 + 0] = (float)c0; deg[i0 + 1] = (float)c1;
        deg[i0 + 2] = (float)c2; deg[i0 + 3] = (float)c3;
    }
}

// ---------------- gw1 scan: gp[h] += sum_f indiv_flat[f] * gw1[f][h] ----------------
__global__ __launch_bounds__(256) void gw1_scan(
    const float* __restrict__ indiv, const float* __restrict__ gw1,
    float* __restrict__ gp)
{
    const int b = blockIdx.x, t = threadIdx.x;
    const int rl = t >> 6;              // 0..3 row-within-group
    const int c4 = (t & 63) << 2;       // column base
    const float* gb = gw1 + (size_t)b * (HID * 256);
    const float* ib = indiv + (size_t)b * 256;
    float4 acc = make_float4(0.f, 0.f, 0.f, 0.f);
#pragma unroll 4
    for (int it = 0; it < 64; ++it) {
        const int r = it * 4 + rl;
        const float s = ib[r];
        float4 w = *(const float4*)(gb + (size_t)r * HID + c4);
        acc.x += s * w.x; acc.y += s * w.y; acc.z += s * w.z; acc.w += s * w.w;
    }
    __shared__ float red[4][256];
    *(float4*)&red[rl][c4] = acc;
    __syncthreads();
    float v = red[0][t] + red[1][t] + red[2][t] + red[3][t];
    atomicAdd(&gp[t], v);
}

// ---------------- glob MLP + fold glob into fused-layer bias ----------------
__global__ __launch_bounds__(256) void glob_k(
    const float* __restrict__ gp, const float* __restrict__ gb1,
    const float* __restrict__ gw2, const float* __restrict__ gb2,
    const float* __restrict__ fw1, const float* __restrict__ fb1,
    float* __restrict__ fbias)
{
    __shared__ float s1[256], s2[256];
    const int t = threadIdx.x;
    s1[t] = fmaxf(gp[t] + gb1[t], 0.f);
    __syncthreads();
    float a = gb2[t];
#pragma unroll 8
    for (int k = 0; k < HID; ++k) a += s1[k] * gw2[(size_t)k * HID + t];
    s2[t] = a;
    __syncthreads();
    float b = fb1[t];
#pragma unroll 8
    for (int k = 0; k < HID; ++k) b += s2[k] * fw1[(size_t)(512 + k) * HID + t];
    fbias[t] = b;
}

extern "C" void kernel_launch(void* const* d_in, const int* in_sizes, int n_in,
                              void* d_out, int out_size, void* d_ws, size_t ws_size,
                              hipStream_t stream) {
    const float* obs = (const float*)d_in[0];
    const int*   adj = (const int*)d_in[1];
    const float* iw1 = (const float*)d_in[2];
    const float* ib1 = (const float*)d_in[3];
    const float* iw2 = (const float*)d_in[4];
    const float* ib2 = (const float*)d_in[5];
    const float* lw1 = (const float*)d_in[6];
    const float* lb1 = (const float*)d_in[7];
    const float* lw2 = (const float*)d_in[8];
    const float* lb2 = (const float*)d_in[9];
    const float* gw1 = (const float*)d_in[10];
    const float* gb1 = (const float*)d_in[11];
    const float* gw2 = (const float*)d_in[12];
    const float* gb2 = (const float*)d_in[13];
    const float* fw1 = (const float*)d_in[14];
    const float* fb1 = (const float*)d_in[15];
    const float* fw2 = (const float*)d_in[16];
    const float* fb2 = (const float*)d_in[17];
    float* out = (float*)d_out;

    float* ws = (float*)d_ws;
    const size_t NH = (size_t)NROWS * HID;  // 524288
    float* h1    = ws;
    float* indiv = ws + NH;
    float* neigh = ws + 2 * NH;
    float* l1    = ws + 3 * NH;
    float* loc   = ws + 4 * NH;
    float* f1    = ws + 5 * NH;
    float* deg   = ws + 6 * NH;
    float* gp    = ws + 6 * NH + 4096;
    float* fbias = ws + 6 * NH + 4096 + 256;

    dim3 ggrid(NROWS / 64, HID / 64);  // (32, 4)

    // indiv = relu(obs@iw1+ib1)@iw2+ib2
    gemm64<<<ggrid, 256, 0, stream>>>(obs, iw1, ib1, nullptr, h1, OBSD, F_BIAS | F_RELU, nullptr, nullptr);
    gemm64<<<ggrid, 256, 0, stream>>>(h1, iw2, ib2, nullptr, indiv, HID, F_BIAS, nullptr, nullptr);

    // glob pre-activation: gp = indiv_flat @ gw1 (atomic accumulate)
    hipMemsetAsync(gp, 0, HID * sizeof(float), stream);
    gw1_scan<<<2048, 256, 0, stream>>>(indiv, gw1, gp);

    // neighbor mean + degree
    neigh_k<<<NROWS / 4, 256, 0, stream>>>(adj, indiv, neigh, deg);

    // glob MLP, folded into fused-layer bias
    glob_k<<<1, 256, 0, stream>>>(gp, gb1, gw2, gb2, fw1, fb1, fbias);

    // local = relu(indiv@lw1a + neigh@lw1b + lb1)@lw2 + lb2, fallback indiv when deg==0
    gemm64<<<ggrid, 256, 0, stream>>>(indiv, lw1, nullptr, nullptr, l1, HID, 0, nullptr, nullptr);
    gemm64<<<ggrid, 256, 0, stream>>>(neigh, lw1 + (size_t)HID * HID, lb1, l1, l1, HID, F_ACC | F_BIAS | F_RELU, nullptr, nullptr);
    gemm64<<<ggrid, 256, 0, stream>>>(l1, lw2, lb2, nullptr, loc, HID, F_BIAS | F_SEL, deg, indiv);

    // out = relu(indiv@fw1a + loc@fw1b + fbias)@fw2 + fb2   (glob part folded into fbias)
    gemm64<<<ggrid, 256, 0, stream>>>(indiv, fw1, nullptr, nullptr, f1, HID, 0, nullptr, nullptr);
    gemm64<<<ggrid, 256, 0, stream>>>(loc, fw1 + (size_t)HID * HID, fbias, f1, f1, HID, F_ACC | F_BIAS | F_RELU, nullptr, nullptr);
    gemm64<<<ggrid, 256, 0, stream>>>(f1, fw2, fb2, nullptr, out, HID, F_BIAS, nullptr, nullptr);
}